// Round 11
// baseline (6201.763 us; speedup 1.0000x reference)
//
#include <hip/hip_runtime.h>

// Attention B=2,H=16,S=2048,D=64 fp32; out = softmax(where(mask, clip(QK^T/8,1e-9,1e9), -1e9)) V
// d_out = [out | p_attn] fp32.
// r8 structure with BQ=128 (two 64-row q-subtiles per wave) to amortize per-chunk
// fixed costs (staging, prefetch, barrier) over 2x MFMA/exp work.
// Pass A: QK^T + exp + esum + unnormalized PV (raw mask, reg ping-pong; bits -> MBh).
// Pass B: recompute QK^T (K L2-resident), p = exp*inv, stream p (bits from MBh).

#define B_ 2
#define H_ 16
#define S_ 2048
#define D_ 64
#define BQ 128           // q rows per block (2 subtiles of 64)
#define NQT (S_ / BQ)    // 16 q tiles per (b,h)
#define NCH (S_ / 64)    // 32 k-chunks of 64

typedef __attribute__((ext_vector_type(8))) short bf16x8;
typedef __attribute__((ext_vector_type(4))) float f32x4;

__device__ inline short f2bf(float f) {
    unsigned u = __float_as_uint(f);
    u = (u + 0x7FFFu + ((u >> 16) & 1u)) >> 16;   // RNE
    return (short)u;
}

// ---- row-major [64][64] tile load (fp32 global -> 4 float4 regs), coalesced ----
__device__ __forceinline__ void loadRM(const float* __restrict__ src, int tid, float4* r) {
#pragma unroll
    for (int it = 0; it < 2; ++it) {
        const int g = it * 256 + tid;
        const float4* s4 = reinterpret_cast<const float4*>(src + (g >> 3) * 64 + (g & 7) * 8);
        r[it * 2]     = s4[0];
        r[it * 2 + 1] = s4[1];
    }
}
// regs -> bf16 LDS row-major, 16B-granule XOR swizzle
__device__ __forceinline__ void writeRM(short* dst, int tid, const float4* r) {
#pragma unroll
    for (int it = 0; it < 2; ++it) {
        const int g = it * 256 + tid;
        const int row = g >> 3, b = g & 7;
        const float4 a = r[it * 2], c = r[it * 2 + 1];
        bf16x8 v;
        v[0]=f2bf(a.x); v[1]=f2bf(a.y); v[2]=f2bf(a.z); v[3]=f2bf(a.w);
        v[4]=f2bf(c.x); v[5]=f2bf(c.y); v[6]=f2bf(c.z); v[7]=f2bf(c.w);
        *reinterpret_cast<bf16x8*>(&dst[row * 64 + ((b ^ (row & 7)) << 3)]) = v;
    }
}
// V tile: global row-major -> regs (coalesced: 64 lanes read 256B lines)
__device__ __forceinline__ void loadVc(const float* __restrict__ src, int tid, float* vr) {
    const int d = tid & 63, kq = tid >> 6;
#pragma unroll
    for (int i = 0; i < 16; ++i)
        vr[i] = src[(size_t)(kq * 16 + i) * 64 + d];
}
// regs -> d-major [64 d][64 k] bf16 LDS, XOR granule swizzle
__device__ __forceinline__ void writeVc(short* dst, int tid, const float* vr) {
    const int d = tid & 63, kq = tid >> 6;
#pragma unroll
    for (int h = 0; h < 2; ++h) {
        bf16x8 v;
#pragma unroll
        for (int i = 0; i < 8; ++i) v[i] = f2bf(vr[h * 8 + i]);
        *reinterpret_cast<bf16x8*>(&dst[d * 64 + (((2 * kq + h) ^ (d & 7)) << 3)]) = v;
    }
}

// =============== pass A body: 2 subtiles of {QK^T, exp, esum, PV} ===============
#define BODY_A(CH, CUR, MVC, MVN)                                              \
  {                                                                            \
    const int ch_ = (CH);                                                      \
    /* prefetch next chunk's mask ints (consumed next body) */                 \
    if (ch_ + 1 < NCH) {                                                       \
      _Pragma("unroll") for (int st = 0; st < 2; ++st)                         \
      _Pragma("unroll") for (int kc = 0; kc < 4; ++kc)                         \
      _Pragma("unroll") for (int j = 0; j < 4; ++j)                            \
        MVN[st*16 + kc*4 + j] =                                                \
          Mb[mrow0 + (size_t)(st*64 + j)*S_ + (size_t)(ch_+1)*64 + kc*16 + c16]; \
    }                                                                          \
    __builtin_amdgcn_s_setprio(1);                                             \
    _Pragma("unroll") for (int st = 0; st < 2; ++st) {                         \
      _Pragma("unroll") for (int kc = 0; kc < 4; ++kc) {                       \
        const int kr = kc*16 + c16;                                            \
        bf16x8 kf0 = *(const bf16x8*)&Ks[CUR][kr*64 + ((g16 ^ rsw) << 3)];     \
        bf16x8 kf1 = *(const bf16x8*)&Ks[CUR][kr*64 + (((4+g16) ^ rsw) << 3)]; \
        f32x4 acc = {0.f,0.f,0.f,0.f};                                         \
        acc = __builtin_amdgcn_mfma_f32_16x16x32_bf16(qf[st][0], kf0, acc, 0,0,0); \
        acc = __builtin_amdgcn_mfma_f32_16x16x32_bf16(qf[st][1], kf1, acc, 0,0,0); \
        _Pragma("unroll") for (int j = 0; j < 4; ++j) {                        \
          float s = acc[j] * 0.125f;                                           \
          s = fminf(fmaxf(s, 1e-9f), 1e9f);                                    \
          const float e = MVC[st*16 + kc*4 + j] ? __expf(s) : 0.f;             \
          esum[st][j] += e;                                                    \
          const int row = g16*4 + j, cg = kc*16 + c16;                         \
          Ps[wv][row*64 + ((cg & 7) | (((cg >> 3) ^ (row & 7)) << 3))] = f2bf(e); \
        }                                                                      \
      }                                                                        \
      _Pragma("unroll") for (int ks = 0; ks < 2; ++ks) {                       \
        bf16x8 pa = *(const bf16x8*)&Ps[wv][c16*64 + (((ks*4+g16) ^ rsw) << 3)]; \
        _Pragma("unroll") for (int dt = 0; dt < 4; ++dt) {                     \
          const int vr_ = dt*16 + c16;                                         \
          bf16x8 vb = *(const bf16x8*)&Vs[CUR][vr_*64 + (((ks*4+g16) ^ (vr_ & 7)) << 3)]; \
          o[st][dt] = __builtin_amdgcn_mfma_f32_16x16x32_bf16(pa, vb, o[st][dt], 0,0,0); \
        }                                                                      \
      }                                                                        \
    }                                                                          \
    __builtin_amdgcn_s_setprio(0);                                             \
    /* pack current mask bits for pass B */                                    \
    {                                                                          \
      unsigned pb0 = 0, pb1 = 0;                                               \
      _Pragma("unroll") for (int i = 0; i < 16; ++i) {                         \
        pb0 |= (MVC[i]      != 0 ? 1u : 0u) << i;                              \
        pb1 |= (MVC[16 + i] != 0 ? 1u : 0u) << i;                              \
      }                                                                        \
      *(unsigned*)&MBh[tid*66 + 2*ch_] = pb0 | (pb1 << 16);                    \
    }                                                                          \
    if (ch_ + 1 < NCH) { writeRM((short*)Ks[(CUR)^1], tid, kA);                \
                         writeVc((short*)Vs[(CUR)^1], tid, vA); }              \
    if (ch_ + 2 < NCH) { loadRM(Kb + (size_t)(ch_+2)*4096, tid, kA);           \
                         loadVc(Vb + (size_t)(ch_+2)*4096, tid, vA); }         \
    __syncthreads();                                                           \
  }

// =============== pass B body: 2 subtiles of {QK^T, normalize, stream p} ===============
#define BODY_B(CH, CUR)                                                        \
  {                                                                            \
    const int ch_ = (CH);                                                      \
    const unsigned mwv = *(const unsigned*)&MBh[tid*66 + 2*ch_];               \
    __builtin_amdgcn_s_setprio(1);                                             \
    _Pragma("unroll") for (int st = 0; st < 2; ++st) {                         \
      const unsigned mw_ = st ? (mwv >> 16) : (mwv & 0xffffu);                 \
      _Pragma("unroll") for (int kc = 0; kc < 4; ++kc) {                       \
        const int kr = kc*16 + c16;                                            \
        bf16x8 kf0 = *(const bf16x8*)&Ks[CUR][kr*64 + ((g16 ^ rsw) << 3)];     \
        bf16x8 kf1 = *(const bf16x8*)&Ks[CUR][kr*64 + (((4+g16) ^ rsw) << 3)]; \
        f32x4 acc = {0.f,0.f,0.f,0.f};                                         \
        acc = __builtin_amdgcn_mfma_f32_16x16x32_bf16(qf[st][0], kf0, acc, 0,0,0); \
        acc = __builtin_amdgcn_mfma_f32_16x16x32_bf16(qf[st][1], kf1, acc, 0,0,0); \
        _Pragma("unroll") for (int j = 0; j < 4; ++j) {                        \
          float s = acc[j] * 0.125f;                                           \
          s = fminf(fmaxf(s, 1e-9f), 1e9f);                                    \
          const float p = ((mw_ >> (kc*4 + j)) & 1u) ? __expf(s) * inv[st][j] : 0.f; \
          Pg[(size_t)(st*64 + wv*16 + g16*4 + j)*S_ + (size_t)ch_*64 + kc*16 + c16] = p; \
        }                                                                      \
      }                                                                        \
    }                                                                          \
    __builtin_amdgcn_s_setprio(0);                                             \
    if (ch_ + 1 < NCH) writeRM((short*)Ks[(CUR)^1], tid, kA);                  \
    if (ch_ + 2 < NCH) loadRM(Kb + (size_t)(ch_+2)*4096, tid, kA);             \
    __syncthreads();                                                           \
  }

__global__ __launch_bounds__(256, 2) void attn_fused(
    const float* __restrict__ Q, const float* __restrict__ K,
    const float* __restrict__ V, const int* __restrict__ M,
    float* __restrict__ Out, float* __restrict__ P)
{
    __shared__ short Ks[2][4096];            // 16 KB (also Q staging in prologue)
    __shared__ short Vs[2][4096];            // 16 KB (d-major)
    __shared__ short Ps[4][1024];            // 8 KB per-wave P scratch
    __shared__ unsigned short MBh[256 * 66]; // 33 KB mask bits (2 u16/chunk/thread)

    const int tid  = threadIdx.x;
    const int wv   = tid >> 6;
    const int lane = tid & 63;
    const int g16  = lane >> 4;
    const int c16  = lane & 15;
    const int rsw  = c16 & 7;

    // XCD-aware bijective swizzle (512 % 8 == 0)
    const int wid = (blockIdx.x & 7) * (gridDim.x >> 3) + (blockIdx.x >> 3);
    const int bh = wid >> 4;       // 16 q-tiles per bh
    const int qt = wid & 15;
    const int qbase = qt * BQ;

    const float* Qb = Q + ((size_t)bh * S_ + qbase) * D_;
    const float* Kb = K + (size_t)bh * S_ * D_;
    const float* Vb = V + (size_t)bh * S_ * D_;
    const int*   Mb = M + (size_t)(bh >> 4) * S_ * S_;
    float*       Pg = P + ((size_t)bh * S_ + qbase) * S_;
    float*       Og = Out + ((size_t)bh * S_ + qbase) * D_;

    float4 kA[4]; float vA[16];
    bf16x8 qf[2][2];

    // ---- prologue: stage Q (2 subtiles) into Ks, read fragments, then K0/V0 ----
    {
        float4 qA[8];
        loadRM(Qb,          tid, qA);
        loadRM(Qb + 64*64,  tid, qA + 4);
        loadRM(Kb, tid, kA);
        loadVc(Vb, tid, vA);
        short* KsF = (short*)Ks;
        writeRM(KsF,        tid, qA);
        writeRM(KsF + 4096, tid, qA + 4);
    }
    __syncthreads();
    {
        const short* KsF = (const short*)Ks;
        const int qrow = wv * 16 + c16;
#pragma unroll
        for (int st = 0; st < 2; ++st) {
            qf[st][0] = *(const bf16x8*)&KsF[st*4096 + qrow*64 + ((g16 ^ rsw) << 3)];
            qf[st][1] = *(const bf16x8*)&KsF[st*4096 + qrow*64 + (((4+g16) ^ rsw) << 3)];
        }
    }
    __syncthreads();   // everyone done reading Q before Ks[0] is overwritten
    writeRM((short*)Ks[0], tid, kA);
    writeVc((short*)Vs[0], tid, vA);
    loadRM(Kb + 4096, tid, kA);      // ch1 in regs
    loadVc(Vb + 4096, tid, vA);

    const size_t mrow0 = (size_t)(qbase + wv*16 + g16*4) * S_;
    int mvA[32], mvB[32];
#pragma unroll
    for (int st = 0; st < 2; ++st)
#pragma unroll
        for (int kc = 0; kc < 4; ++kc)
#pragma unroll
            for (int j = 0; j < 4; ++j)
                mvA[st*16 + kc*4 + j] = Mb[mrow0 + (size_t)(st*64 + j)*S_ + kc*16 + c16];
    __syncthreads();

    // =============== PASS A ===============
    float esum[2][4] = {{0.f,0.f,0.f,0.f},{0.f,0.f,0.f,0.f}};
    f32x4 o[2][4];
#pragma unroll
    for (int st = 0; st < 2; ++st)
#pragma unroll
        for (int dt = 0; dt < 4; ++dt) o[st][dt] = f32x4{0.f,0.f,0.f,0.f};

    for (int t = 0; t < NCH/2; ++t) {
        BODY_A(2*t,     0, mvA, mvB)
        BODY_A(2*t + 1, 1, mvB, mvA)
    }

    float inv[2][4];
#pragma unroll
    for (int st = 0; st < 2; ++st)
#pragma unroll
        for (int j = 0; j < 4; ++j) {
            float v = esum[st][j];
            v += __shfl_xor(v, 1);
            v += __shfl_xor(v, 2);
            v += __shfl_xor(v, 4);
            v += __shfl_xor(v, 8);
            inv[st][j] = 1.0f / v;
        }
#pragma unroll
    for (int st = 0; st < 2; ++st)
#pragma unroll
        for (int dt = 0; dt < 4; ++dt)
#pragma unroll
            for (int j = 0; j < 4; ++j)
                Og[(size_t)(st*64 + wv*16 + g16*4 + j) * D_ + dt*16 + c16]
                    = o[st][dt][j] * inv[st][j];

    // =============== PASS B prologue: restart K pipeline ===============
    loadRM(Kb, tid, kA);          // ch0
    writeRM((short*)Ks[0], tid, kA);
    loadRM(Kb + 4096, tid, kA);   // ch1
    __syncthreads();

    for (int t = 0; t < NCH/2; ++t) {
        BODY_B(2*t,     0)
        BODY_B(2*t + 1, 1)
    }
}

extern "C" void kernel_launch(void* const* d_in, const int* in_sizes, int n_in,
                              void* d_out, int out_size, void* d_ws, size_t ws_size,
                              hipStream_t stream) {
    const float* Q = (const float*)d_in[0];
    const float* K = (const float*)d_in[1];
    const float* V = (const float*)d_in[2];
    const int*   M = (const int*)d_in[3];

    float* Out = (float*)d_out;
    float* P   = (float*)d_out + (size_t)B_ * H_ * S_ * D_;

    hipLaunchKernelGGL(attn_fused, dim3(B_ * H_ * NQT), dim3(256), 0, stream,
                       Q, K, V, M, Out, P);
}

// Round 13
// 534.125 us; speedup vs baseline: 11.6111x; 11.6111x over previous
//
#include <hip/hip_runtime.h>

// Attention B=2,H=16,S=2048,D=64 fp32; out = softmax(where(mask, clip(QK^T/8,1e-9,1e9), -1e9)) V
// d_out = [out | p_attn] fp32.
// r8 structure (249us anchor) with ONE lever: MBh mask-bit LDS cache (17KB) moved
// into 16 u32 registers (mbits, statically indexed after full unroll).
// LDS 57KB -> 40KB => 3+ blocks/CU (launch_bounds(256,3)).

#define B_ 2
#define H_ 16
#define S_ 2048
#define D_ 64
#define BQ 64            // q rows per block
#define NQT (S_ / BQ)    // 32 q tiles per (b,h)
#define NCH (S_ / 64)    // 32 k-chunks of 64

typedef __attribute__((ext_vector_type(8))) short bf16x8;
typedef __attribute__((ext_vector_type(4))) float f32x4;

__device__ inline short f2bf(float f) {
    unsigned u = __float_as_uint(f);
    u = (u + 0x7FFFu + ((u >> 16) & 1u)) >> 16;   // RNE
    return (short)u;
}

// ---- row-major [64][64] tile load (fp32 global -> 4 float4 regs), coalesced ----
__device__ __forceinline__ void loadRM(const float* __restrict__ src, int tid, float4* r) {
#pragma unroll
    for (int it = 0; it < 2; ++it) {
        const int g = it * 256 + tid;
        const float4* s4 = reinterpret_cast<const float4*>(src + (g >> 3) * 64 + (g & 7) * 8);
        r[it * 2]     = s4[0];
        r[it * 2 + 1] = s4[1];
    }
}
// regs -> bf16 LDS row-major, 16B-granule XOR swizzle
__device__ __forceinline__ void writeRM(short* dst, int tid, const float4* r) {
#pragma unroll
    for (int it = 0; it < 2; ++it) {
        const int g = it * 256 + tid;
        const int row = g >> 3, b = g & 7;
        const float4 a = r[it * 2], c = r[it * 2 + 1];
        bf16x8 v;
        v[0]=f2bf(a.x); v[1]=f2bf(a.y); v[2]=f2bf(a.z); v[3]=f2bf(a.w);
        v[4]=f2bf(c.x); v[5]=f2bf(c.y); v[6]=f2bf(c.z); v[7]=f2bf(c.w);
        *reinterpret_cast<bf16x8*>(&dst[row * 64 + ((b ^ (row & 7)) << 3)]) = v;
    }
}
// V tile: global row-major -> regs (coalesced: 64 lanes read 256B lines)
__device__ __forceinline__ void loadVc(const float* __restrict__ src, int tid, float* vr) {
    const int d = tid & 63, kq = tid >> 6;
#pragma unroll
    for (int i = 0; i < 16; ++i)
        vr[i] = src[(size_t)(kq * 16 + i) * 64 + d];
}
// regs -> d-major [64 d][64 k] bf16 LDS, XOR granule swizzle
__device__ __forceinline__ void writeVc(short* dst, int tid, const float* vr) {
    const int d = tid & 63, kq = tid >> 6;
#pragma unroll
    for (int h = 0; h < 2; ++h) {
        bf16x8 v;
#pragma unroll
        for (int i = 0; i < 8; ++i) v[i] = f2bf(vr[h * 8 + i]);
        *reinterpret_cast<bf16x8*>(&dst[d * 64 + (((2 * kq + h) ^ (d & 7)) << 3)]) = v;
    }
}

// =============== pass A body ===============
// bits for chunk CH come from mbits[CH>>1] (packed in previous body / prologue);
// this body prefetches chunk CH+1's raw ints and packs them at the end.
// NOTE: loops using these macros are fully unrolled, so ch_ folds to a constant
// and all mbits indexing is static.
#define BODY_A(CH, CUR)                                                        \
  {                                                                            \
    const int ch_ = (CH);                                                      \
    int tm[16];                                                                \
    if (ch_ + 1 < NCH) {                                                       \
      _Pragma("unroll") for (int kc = 0; kc < 4; ++kc)                         \
      _Pragma("unroll") for (int j = 0; j < 4; ++j)                            \
        tm[kc*4+j] = Mb[mrow0 + (size_t)j*S_ + (size_t)(ch_+1)*64 + kc*16 + c16]; \
    }                                                                          \
    const unsigned mw_ = (ch_ & 1) ? (mbits[ch_>>1] >> 16) : (mbits[ch_>>1] & 0xffffu); \
    __builtin_amdgcn_s_setprio(1);                                             \
    _Pragma("unroll") for (int kc = 0; kc < 4; ++kc) {                         \
      const int kr = kc*16 + c16;                                              \
      bf16x8 kf0 = *(const bf16x8*)&Ks[CUR][kr*64 + ((g16 ^ rsw) << 3)];       \
      bf16x8 kf1 = *(const bf16x8*)&Ks[CUR][kr*64 + (((4+g16) ^ rsw) << 3)];   \
      f32x4 acc = {0.f,0.f,0.f,0.f};                                           \
      acc = __builtin_amdgcn_mfma_f32_16x16x32_bf16(qf0, kf0, acc, 0,0,0);     \
      acc = __builtin_amdgcn_mfma_f32_16x16x32_bf16(qf1, kf1, acc, 0,0,0);     \
      _Pragma("unroll") for (int j = 0; j < 4; ++j) {                          \
        float s = acc[j] * 0.125f;                                             \
        s = fminf(fmaxf(s, 1e-9f), 1e9f);                                      \
        const float e = ((mw_ >> (kc*4 + j)) & 1u) ? __expf(s) : 0.f;          \
        esum[j] += e;                                                          \
        const int row = g16*4 + j, cg = kc*16 + c16;                           \
        Ps[wv][row*64 + ((cg & 7) | (((cg >> 3) ^ (row & 7)) << 3))] = f2bf(e);\
      }                                                                        \
    }                                                                          \
    _Pragma("unroll") for (int ks = 0; ks < 2; ++ks) {                         \
      bf16x8 pa = *(const bf16x8*)&Ps[wv][c16*64 + (((ks*4+g16) ^ rsw) << 3)]; \
      _Pragma("unroll") for (int dt = 0; dt < 4; ++dt) {                       \
        const int vr_ = dt*16 + c16;                                           \
        bf16x8 vb = *(const bf16x8*)&Vs[CUR][vr_*64 + (((ks*4+g16) ^ (vr_ & 7)) << 3)]; \
        o[dt] = __builtin_amdgcn_mfma_f32_16x16x32_bf16(pa, vb, o[dt], 0,0,0); \
      }                                                                        \
    }                                                                          \
    __builtin_amdgcn_s_setprio(0);                                             \
    if (ch_ + 1 < NCH) {                                                       \
      unsigned wb = 0;                                                         \
      _Pragma("unroll") for (int i = 0; i < 16; ++i)                           \
        wb |= (tm[i] != 0 ? 1u : 0u) << i;                                     \
      if ((ch_ + 1) & 1) mbits[(ch_+1)>>1] |= (wb << 16);                      \
      else               mbits[(ch_+1)>>1]  = wb;                              \
    }                                                                          \
    if (ch_ + 1 < NCH) { writeRM((short*)Ks[(CUR)^1], tid, kA);                \
                         writeVc((short*)Vs[(CUR)^1], tid, vA); }              \
    if (ch_ + 2 < NCH) { loadRM(Kb + (size_t)(ch_+2)*4096, tid, kA);           \
                         loadVc(Vb + (size_t)(ch_+2)*4096, tid, vA); }         \
    __syncthreads();                                                           \
  }

// =============== pass B body: recompute, normalize, stream p ===============
#define BODY_B(CH, CUR)                                                        \
  {                                                                            \
    const int ch_ = (CH);                                                      \
    const unsigned mw_ = (ch_ & 1) ? (mbits[ch_>>1] >> 16) : (mbits[ch_>>1] & 0xffffu); \
    __builtin_amdgcn_s_setprio(1);                                             \
    _Pragma("unroll") for (int kc = 0; kc < 4; ++kc) {                         \
      const int kr = kc*16 + c16;                                              \
      bf16x8 kf0 = *(const bf16x8*)&Ks[CUR][kr*64 + ((g16 ^ rsw) << 3)];       \
      bf16x8 kf1 = *(const bf16x8*)&Ks[CUR][kr*64 + (((4+g16) ^ rsw) << 3)];   \
      f32x4 acc = {0.f,0.f,0.f,0.f};                                           \
      acc = __builtin_amdgcn_mfma_f32_16x16x32_bf16(qf0, kf0, acc, 0,0,0);     \
      acc = __builtin_amdgcn_mfma_f32_16x16x32_bf16(qf1, kf1, acc, 0,0,0);     \
      _Pragma("unroll") for (int j = 0; j < 4; ++j) {                          \
        float s = acc[j] * 0.125f;                                             \
        s = fminf(fmaxf(s, 1e-9f), 1e9f);                                      \
        const float p = ((mw_ >> (kc*4 + j)) & 1u) ? __expf(s) * inv[j] : 0.f; \
        Pg[(size_t)(wv*16 + g16*4 + j)*S_ + (size_t)ch_*64 + kc*16 + c16] = p; \
      }                                                                        \
    }                                                                          \
    __builtin_amdgcn_s_setprio(0);                                             \
    if (ch_ + 1 < NCH) writeRM((short*)Ks[(CUR)^1], tid, kA);                  \
    if (ch_ + 2 < NCH) loadRM(Kb + (size_t)(ch_+2)*4096, tid, kA);             \
    __syncthreads();                                                           \
  }

__global__ __launch_bounds__(256, 3) void attn_fused(
    const float* __restrict__ Q, const float* __restrict__ K,
    const float* __restrict__ V, const int* __restrict__ M,
    float* __restrict__ Out, float* __restrict__ P)
{
    __shared__ short Ks[2][4096];            // 16 KB (also Q staging in prologue)
    __shared__ short Vs[2][4096];            // 16 KB (d-major)
    __shared__ short Ps[4][1024];            // 8 KB per-wave P scratch
    // total 40 KB -> up to 4 blocks/CU

    const int tid  = threadIdx.x;
    const int wv   = tid >> 6;
    const int lane = tid & 63;
    const int g16  = lane >> 4;
    const int c16  = lane & 15;
    const int rsw  = c16 & 7;

    // XCD-aware bijective swizzle (1024 % 8 == 0)
    const int wid = (blockIdx.x & 7) * (gridDim.x >> 3) + (blockIdx.x >> 3);
    const int bh = wid >> 5;
    const int qt = wid & 31;
    const int qbase = qt * BQ;

    const float* Qb = Q + ((size_t)bh * S_ + qbase) * D_;
    const float* Kb = K + (size_t)bh * S_ * D_;
    const float* Vb = V + (size_t)bh * S_ * D_;
    const int*   Mb = M + (size_t)(bh >> 4) * S_ * S_;
    float*       Pg = P + ((size_t)bh * S_ + qbase) * S_;
    float*       Og = Out + ((size_t)bh * S_ + qbase) * D_;

    float4 kA[4]; float vA[16];
    unsigned mbits[16];   // 512 mask bits; statically indexed (loops fully unrolled)

    // ---- prologue: Q staged via Ps; K/V chunk 0 staged; chunk 1 in flight ----
    {
        float4 qA[4];
        loadRM(Qb, tid, qA);
        loadRM(Kb, tid, kA);
        loadVc(Vb, tid, vA);
        writeRM(&Ps[0][0], tid, qA);
    }
    __syncthreads();
    const int qrow = wv * 16 + c16;
    const short* Qst = &Ps[0][0];
    const bf16x8 qf0 = *(const bf16x8*)&Qst[qrow*64 + ((g16 ^ rsw) << 3)];
    const bf16x8 qf1 = *(const bf16x8*)&Qst[qrow*64 + (((4+g16) ^ rsw) << 3)];
    writeRM((short*)Ks[0], tid, kA);
    writeVc((short*)Vs[0], tid, vA);
    loadRM(Kb + 4096, tid, kA);      // ch1 in regs
    loadVc(Vb + 4096, tid, vA);

    const size_t mrow0 = (size_t)(qbase + wv*16 + g16*4) * S_;
    {   // chunk-0 mask bits
        unsigned wb = 0;
#pragma unroll
        for (int kc = 0; kc < 4; ++kc)
#pragma unroll
            for (int j = 0; j < 4; ++j)
                wb |= (Mb[mrow0 + (size_t)j*S_ + kc*16 + c16] != 0 ? 1u : 0u) << (kc*4+j);
        mbits[0] = wb;
    }
    __syncthreads();

    // =============== PASS A ===============
    float esum[4] = {0.f, 0.f, 0.f, 0.f};
    f32x4 o[4];
#pragma unroll
    for (int dt = 0; dt < 4; ++dt) o[dt] = f32x4{0.f,0.f,0.f,0.f};

#pragma unroll
    for (int t = 0; t < NCH/2; ++t) {
        BODY_A(2*t,     0)
        BODY_A(2*t + 1, 1)
    }

    float inv[4];
#pragma unroll
    for (int j = 0; j < 4; ++j) {
        float v = esum[j];
        v += __shfl_xor(v, 1);
        v += __shfl_xor(v, 2);
        v += __shfl_xor(v, 4);
        v += __shfl_xor(v, 8);
        inv[j] = 1.0f / v;
    }
#pragma unroll
    for (int dt = 0; dt < 4; ++dt)
#pragma unroll
        for (int j = 0; j < 4; ++j)
            Og[(size_t)(wv*16 + g16*4 + j) * D_ + dt*16 + c16] = o[dt][j] * inv[j];

    // =============== PASS B prologue: restart K pipeline ===============
    loadRM(Kb, tid, kA);          // ch0
    writeRM((short*)Ks[0], tid, kA);
    loadRM(Kb + 4096, tid, kA);   // ch1
    __syncthreads();

#pragma unroll
    for (int t = 0; t < NCH/2; ++t) {
        BODY_B(2*t,     0)
        BODY_B(2*t + 1, 1)
    }
}

extern "C" void kernel_launch(void* const* d_in, const int* in_sizes, int n_in,
                              void* d_out, int out_size, void* d_ws, size_t ws_size,
                              hipStream_t stream) {
    const float* Q = (const float*)d_in[0];
    const float* K = (const float*)d_in[1];
    const float* V = (const float*)d_in[2];
    const int*   M = (const int*)d_in[3];

    float* Out = (float*)d_out;
    float* P   = (float*)d_out + (size_t)B_ * H_ * S_ * D_;

    hipLaunchKernelGGL(attn_fused, dim3(B_ * H_ * NQT), dim3(256), 0, stream,
                       Q, K, V, M, Out, P);
}

// Round 14
// 262.367 us; speedup vs baseline: 23.6377x; 2.0358x over previous
//
#include <hip/hip_runtime.h>

// Attention B=2,H=16,S=2048,D=64 fp32; out = softmax(where(mask, clip(QK^T/8,1e-9,1e9), -1e9)) V
// d_out = [out | p_attn] fp32.
// r8 anchor (249us) + ONE change: p_attn stores are non-temporal (bypass L3) so
// Infinity Cache retains the 33.5MB mask working set (shared across H=16 heads)
// and K/V, instead of being thrashed by the 537MB p write stream each pass.

#define B_ 2
#define H_ 16
#define S_ 2048
#define D_ 64
#define BQ 64            // q rows per block
#define NQT (S_ / BQ)    // 32 q tiles per (b,h)
#define NCH (S_ / 64)    // 32 k-chunks of 64

typedef __attribute__((ext_vector_type(8))) short bf16x8;
typedef __attribute__((ext_vector_type(4))) float f32x4;

__device__ inline short f2bf(float f) {
    unsigned u = __float_as_uint(f);
    u = (u + 0x7FFFu + ((u >> 16) & 1u)) >> 16;   // RNE
    return (short)u;
}

// ---- row-major [64][64] tile load (fp32 global -> 4 float4 regs), coalesced ----
__device__ __forceinline__ void loadRM(const float* __restrict__ src, int tid, float4* r) {
#pragma unroll
    for (int it = 0; it < 2; ++it) {
        const int g = it * 256 + tid;
        const float4* s4 = reinterpret_cast<const float4*>(src + (g >> 3) * 64 + (g & 7) * 8);
        r[it * 2]     = s4[0];
        r[it * 2 + 1] = s4[1];
    }
}
// regs -> bf16 LDS row-major, 16B-granule XOR swizzle
__device__ __forceinline__ void writeRM(short* dst, int tid, const float4* r) {
#pragma unroll
    for (int it = 0; it < 2; ++it) {
        const int g = it * 256 + tid;
        const int row = g >> 3, b = g & 7;
        const float4 a = r[it * 2], c = r[it * 2 + 1];
        bf16x8 v;
        v[0]=f2bf(a.x); v[1]=f2bf(a.y); v[2]=f2bf(a.z); v[3]=f2bf(a.w);
        v[4]=f2bf(c.x); v[5]=f2bf(c.y); v[6]=f2bf(c.z); v[7]=f2bf(c.w);
        *reinterpret_cast<bf16x8*>(&dst[row * 64 + ((b ^ (row & 7)) << 3)]) = v;
    }
}
// V tile: global row-major -> regs (coalesced: 64 lanes read 256B lines)
__device__ __forceinline__ void loadVc(const float* __restrict__ src, int tid, float* vr) {
    const int d = tid & 63, kq = tid >> 6;
#pragma unroll
    for (int i = 0; i < 16; ++i)
        vr[i] = src[(size_t)(kq * 16 + i) * 64 + d];
}
// regs -> d-major [64 d][64 k] bf16 LDS, XOR granule swizzle
__device__ __forceinline__ void writeVc(short* dst, int tid, const float* vr) {
    const int d = tid & 63, kq = tid >> 6;
#pragma unroll
    for (int h = 0; h < 2; ++h) {
        bf16x8 v;
#pragma unroll
        for (int i = 0; i < 8; ++i) v[i] = f2bf(vr[h * 8 + i]);
        *reinterpret_cast<bf16x8*>(&dst[d * 64 + (((2 * kq + h) ^ (d & 7)) << 3)]) = v;
    }
}

// =============== pass A body: esum + unnormalized PV + mask-bit capture ===============
#define BODY_A(CH, CUR, MVC, MVN)                                              \
  {                                                                            \
    const int ch_ = (CH);                                                      \
    if (ch_ + 1 < NCH) {                                                       \
      _Pragma("unroll") for (int kc = 0; kc < 4; ++kc)                         \
      _Pragma("unroll") for (int j = 0; j < 4; ++j)                            \
        MVN[kc*4+j] = Mb[mrow0 + (size_t)j*S_ + (size_t)(ch_+1)*64 + kc*16 + c16]; \
    }                                                                          \
    __builtin_amdgcn_s_setprio(1);                                             \
    _Pragma("unroll") for (int kc = 0; kc < 4; ++kc) {                         \
      const int kr = kc*16 + c16;                                              \
      bf16x8 kf0 = *(const bf16x8*)&Ks[CUR][kr*64 + ((g16 ^ rsw) << 3)];       \
      bf16x8 kf1 = *(const bf16x8*)&Ks[CUR][kr*64 + (((4+g16) ^ rsw) << 3)];   \
      f32x4 acc = {0.f,0.f,0.f,0.f};                                           \
      acc = __builtin_amdgcn_mfma_f32_16x16x32_bf16(qf0, kf0, acc, 0,0,0);     \
      acc = __builtin_amdgcn_mfma_f32_16x16x32_bf16(qf1, kf1, acc, 0,0,0);     \
      _Pragma("unroll") for (int j = 0; j < 4; ++j) {                          \
        float s = acc[j] * 0.125f;                                             \
        s = fminf(fmaxf(s, 1e-9f), 1e9f);                                      \
        const float e = MVC[kc*4+j] ? __expf(s) : 0.f;                         \
        esum[j] += e;                                                          \
        const int row = g16*4 + j, cg = kc*16 + c16;                           \
        Ps[wv][row*64 + ((cg & 7) | (((cg >> 3) ^ (row & 7)) << 3))] = f2bf(e);\
      }                                                                        \
    }                                                                          \
    _Pragma("unroll") for (int ks = 0; ks < 2; ++ks) {                         \
      bf16x8 pa = *(const bf16x8*)&Ps[wv][c16*64 + (((ks*4+g16) ^ rsw) << 3)]; \
      _Pragma("unroll") for (int dt = 0; dt < 4; ++dt) {                       \
        const int vr_ = dt*16 + c16;                                           \
        bf16x8 vb = *(const bf16x8*)&Vs[CUR][vr_*64 + (((ks*4+g16) ^ (vr_ & 7)) << 3)]; \
        o[dt] = __builtin_amdgcn_mfma_f32_16x16x32_bf16(pa, vb, o[dt], 0,0,0); \
      }                                                                        \
    }                                                                          \
    __builtin_amdgcn_s_setprio(0);                                             \
    {                                                                          \
      unsigned wb = 0;                                                         \
      _Pragma("unroll") for (int i = 0; i < 16; ++i)                           \
        wb |= (MVC[i] != 0 ? 1u : 0u) << i;                                    \
      MBh[tid * 34 + ch_] = (unsigned short)wb;                                \
    }                                                                          \
    if (ch_ + 1 < NCH) { writeRM(Ks[(CUR)^1], tid, kA); writeVc(Vs[(CUR)^1], tid, vA); } \
    if (ch_ + 2 < NCH) { loadRM(Kb + (size_t)(ch_+2)*4096, tid, kA);           \
                         loadVc(Vb + (size_t)(ch_+2)*4096, tid, vA); }         \
    __syncthreads();                                                           \
  }

// =============== pass B body: recompute, normalize, stream p (non-temporal) ===============
#define BODY_B(CH, CUR, MKW)                                                   \
  {                                                                            \
    const int ch_ = (CH);                                                      \
    const unsigned mw_ = (MKW);                                                \
    __builtin_amdgcn_s_setprio(1);                                             \
    _Pragma("unroll") for (int kc = 0; kc < 4; ++kc) {                         \
      const int kr = kc*16 + c16;                                              \
      bf16x8 kf0 = *(const bf16x8*)&Ks[CUR][kr*64 + ((g16 ^ rsw) << 3)];       \
      bf16x8 kf1 = *(const bf16x8*)&Ks[CUR][kr*64 + (((4+g16) ^ rsw) << 3)];   \
      f32x4 acc = {0.f,0.f,0.f,0.f};                                           \
      acc = __builtin_amdgcn_mfma_f32_16x16x32_bf16(qf0, kf0, acc, 0,0,0);     \
      acc = __builtin_amdgcn_mfma_f32_16x16x32_bf16(qf1, kf1, acc, 0,0,0);     \
      _Pragma("unroll") for (int j = 0; j < 4; ++j) {                          \
        float s = acc[j] * 0.125f;                                             \
        s = fminf(fmaxf(s, 1e-9f), 1e9f);                                      \
        const float p = ((mw_ >> (kc*4 + j)) & 1u) ? __expf(s) * inv[j] : 0.f; \
        __builtin_nontemporal_store(p,                                         \
            &Pg[(size_t)(wv*16 + g16*4 + j)*S_ + (size_t)ch_*64 + kc*16 + c16]); \
      }                                                                        \
    }                                                                          \
    __builtin_amdgcn_s_setprio(0);                                             \
    if (ch_ + 1 < NCH) writeRM(Ks[(CUR)^1], tid, kA);                          \
    if (ch_ + 2 < NCH) loadRM(Kb + (size_t)(ch_+2)*4096, tid, kA);             \
    __syncthreads();                                                           \
  }

__global__ __launch_bounds__(256, 2) void attn_fused(
    const float* __restrict__ Q, const float* __restrict__ K,
    const float* __restrict__ V, const int* __restrict__ M,
    float* __restrict__ Out, float* __restrict__ P)
{
    __shared__ short Ks[2][4096];            // 16 KB
    __shared__ short Vs[2][4096];            // 16 KB (d-major)
    __shared__ short Ps[4][1024];            // 8 KB; also Q staging in prologue
    __shared__ unsigned short MBh[256 * 34]; // 17 KB mask bits, padded stride

    const int tid  = threadIdx.x;
    const int wv   = tid >> 6;
    const int lane = tid & 63;
    const int g16  = lane >> 4;
    const int c16  = lane & 15;
    const int rsw  = c16 & 7;

    // XCD-aware bijective swizzle (1024 % 8 == 0)
    const int wid = (blockIdx.x & 7) * (gridDim.x >> 3) + (blockIdx.x >> 3);
    const int bh = wid >> 5;
    const int qt = wid & 31;
    const int qbase = qt * BQ;

    const float* Qb = Q + ((size_t)bh * S_ + qbase) * D_;
    const float* Kb = K + (size_t)bh * S_ * D_;
    const float* Vb = V + (size_t)bh * S_ * D_;
    const int*   Mb = M + (size_t)(bh >> 4) * S_ * S_;
    float*       Pg = P + ((size_t)bh * S_ + qbase) * S_;
    float*       Og = Out + ((size_t)bh * S_ + qbase) * D_;

    float4 kA[4]; float vA[16];

    // ---- prologue: Q staged via Ps; K/V chunk 0 staged; chunk 1 in flight ----
    {
        float4 qA[4];
        loadRM(Qb, tid, qA);
        loadRM(Kb, tid, kA);
        loadVc(Vb, tid, vA);
        writeRM(&Ps[0][0], tid, qA);
    }
    __syncthreads();
    const int qrow = wv * 16 + c16;
    const short* Qst = &Ps[0][0];
    const bf16x8 qf0 = *(const bf16x8*)&Qst[qrow*64 + ((g16 ^ rsw) << 3)];
    const bf16x8 qf1 = *(const bf16x8*)&Qst[qrow*64 + (((4+g16) ^ rsw) << 3)];
    writeRM(Ks[0], tid, kA);
    writeVc(Vs[0], tid, vA);
    loadRM(Kb + 4096, tid, kA);
    loadVc(Vb + 4096, tid, vA);

    const size_t mrow0 = (size_t)(qbase + wv*16 + g16*4) * S_;
    int mv0[16], mv1[16];
#pragma unroll
    for (int kc = 0; kc < 4; ++kc)
#pragma unroll
        for (int j = 0; j < 4; ++j)
            mv0[kc*4+j] = Mb[mrow0 + (size_t)j*S_ + kc*16 + c16];
    __syncthreads();

    // =============== PASS A ===============
    float esum[4] = {0.f, 0.f, 0.f, 0.f};
    f32x4 o[4];
#pragma unroll
    for (int dt = 0; dt < 4; ++dt) o[dt] = f32x4{0.f, 0.f, 0.f, 0.f};

    for (int t = 0; t < NCH/2; ++t) {
        BODY_A(2*t,     0, mv0, mv1)
        BODY_A(2*t + 1, 1, mv1, mv0)
    }

    float inv[4];
#pragma unroll
    for (int j = 0; j < 4; ++j) {
        float v = esum[j];
        v += __shfl_xor(v, 1);
        v += __shfl_xor(v, 2);
        v += __shfl_xor(v, 4);
        v += __shfl_xor(v, 8);
        inv[j] = 1.0f / v;
    }
#pragma unroll
    for (int dt = 0; dt < 4; ++dt)
#pragma unroll
        for (int j = 0; j < 4; ++j)
            Og[(size_t)(wv*16 + g16*4 + j) * D_ + dt*16 + c16] = o[dt][j] * inv[j];

    // =============== PASS B prologue: restart K pipeline ===============
    loadRM(Kb, tid, kA);          // ch0
    writeRM(Ks[0], tid, kA);      // all waves past pass-A final barrier
    loadRM(Kb + 4096, tid, kA);   // ch1
    __syncthreads();

    for (int t = 0; t < NCH/2; ++t) {
        const unsigned w = *(const unsigned*)&MBh[tid * 34 + 2*t];
        BODY_B(2*t,     0, w & 0xffffu)
        BODY_B(2*t + 1, 1, w >> 16)
    }
}

extern "C" void kernel_launch(void* const* d_in, const int* in_sizes, int n_in,
                              void* d_out, int out_size, void* d_ws, size_t ws_size,
                              hipStream_t stream) {
    const float* Q = (const float*)d_in[0];
    const float* K = (const float*)d_in[1];
    const float* V = (const float*)d_in[2];
    const int*   M = (const int*)d_in[3];

    float* Out = (float*)d_out;
    float* P   = (float*)d_out + (size_t)B_ * H_ * S_ * D_;

    hipLaunchKernelGGL(attn_fused, dim3(B_ * H_ * NQT), dim3(256), 0, stream,
                       Q, K, V, M, Out, P);
}